// Round 12
// baseline (49.005 us; speedup 1.0000x reference)
//
#include <hip/hip_runtime.h>
#include <math.h>

// OFDM: per-row 64-pt complex FFT (radix-2 DIF, lane-per-bin), fully
// row-PAIR packed (v_pk_fma_f32 via compiler; no inline asm).
// Cross-lane per 32-bit reg: xor32 -> permlane32_swap, xor16 ->
// permlane16_swap, xor8 -> DPP row_ror:8, xor4 -> ds_swizzle,
// xor2/xor1 -> DPP quad_perm. Stage-4 twiddle = +/-i -> selects.
// Twiddle setup: v_cos_f32/v_sin_f32 in REVOLUTIONS (t/64).
// R11 experiment: NT LOADS + CACHED STORES. Input (134MB) + output (134MB)
// > 256MB L3 -> thrash (65MB refetch + 134MB write-back per iter = 200MB
// HBM). NT loads keep input OUT of L3 so the output working set stays
// fully L3-resident: steady-state HBM traffic = input reads only (~134MB).
// Epilogue packed, bit-reversed domain; scatter-store restores order.

typedef float f32x2 __attribute__((ext_vector_type(2)));
typedef unsigned int uint2v __attribute__((ext_vector_type(2)));

struct LaneConst {
    f32x2 psgn[6];            // stages 0..5 butterfly sign (broadcast pair)
    f32x2 C[4], S[4], Sn[4];  // stages 0..3 twiddle (S = -sin; stage4 = +/-i, stage5 = 1)
    bool  rot4;               // stage-4: this lane multiplies by -i
    f32x2 pw0, pw1, pw2, pw3; // pilot interp weights (broadcast pair)
    int   kk;                 // natural bin index = brev6(lane)
};

__device__ __forceinline__ f32x2 pk_fma(f32x2 a, f32x2 b, f32x2 cc) {
#if __has_builtin(__builtin_elementwise_fma)
    return __builtin_elementwise_fma(a, b, cc);
#else
    return a * b + cc;
#endif
}

template <int CTRL>
__device__ __forceinline__ float dpp_mov(float x) {
    return __int_as_float(__builtin_amdgcn_update_dpp(
        0, __float_as_int(x), CTRL, 0xF, 0xF, true));
}
__device__ __forceinline__ float swz4(float x) {
    return __int_as_float(__builtin_amdgcn_ds_swizzle(__float_as_int(x), 0x101F));
}
__device__ __forceinline__ float rdlane(float x, int l) {
    return __int_as_float(__builtin_amdgcn_readlane(__float_as_int(x), l));
}

// full packed FFT for a row pair (rows r0, r0+1 in .x/.y of zr, zi)
__device__ __forceinline__ void fft_pair(f32x2& zr, f32x2& zi, const LaneConst& c) {
    f32x2 lo, hi, ar, ai, pr, pi;
    // ---- stage 0: xor32 via permlane32_swap; bfly = sgn*hi + lo ----
    {
        uint2v t0 = __builtin_amdgcn_permlane32_swap(
            (unsigned)__float_as_int(zr.x), (unsigned)__float_as_int(zr.x), false, false);
        uint2v t1 = __builtin_amdgcn_permlane32_swap(
            (unsigned)__float_as_int(zr.y), (unsigned)__float_as_int(zr.y), false, false);
        lo = (f32x2){ __int_as_float((int)t0[0]), __int_as_float((int)t1[0]) };
        hi = (f32x2){ __int_as_float((int)t0[1]), __int_as_float((int)t1[1]) };
        ar = pk_fma(c.psgn[0], hi, lo);
        t0 = __builtin_amdgcn_permlane32_swap(
            (unsigned)__float_as_int(zi.x), (unsigned)__float_as_int(zi.x), false, false);
        t1 = __builtin_amdgcn_permlane32_swap(
            (unsigned)__float_as_int(zi.y), (unsigned)__float_as_int(zi.y), false, false);
        lo = (f32x2){ __int_as_float((int)t0[0]), __int_as_float((int)t1[0]) };
        hi = (f32x2){ __int_as_float((int)t0[1]), __int_as_float((int)t1[1]) };
        ai = pk_fma(c.psgn[0], hi, lo);
    }
    zr = pk_fma(ar, c.C[0], ai * c.Sn[0]);
    zi = pk_fma(ai, c.C[0], ar * c.S[0]);
    // ---- stage 1: xor16 via permlane16_swap ----
    {
        uint2v t0 = __builtin_amdgcn_permlane16_swap(
            (unsigned)__float_as_int(zr.x), (unsigned)__float_as_int(zr.x), false, false);
        uint2v t1 = __builtin_amdgcn_permlane16_swap(
            (unsigned)__float_as_int(zr.y), (unsigned)__float_as_int(zr.y), false, false);
        lo = (f32x2){ __int_as_float((int)t0[0]), __int_as_float((int)t1[0]) };
        hi = (f32x2){ __int_as_float((int)t0[1]), __int_as_float((int)t1[1]) };
        ar = pk_fma(c.psgn[1], hi, lo);
        t0 = __builtin_amdgcn_permlane16_swap(
            (unsigned)__float_as_int(zi.x), (unsigned)__float_as_int(zi.x), false, false);
        t1 = __builtin_amdgcn_permlane16_swap(
            (unsigned)__float_as_int(zi.y), (unsigned)__float_as_int(zi.y), false, false);
        lo = (f32x2){ __int_as_float((int)t0[0]), __int_as_float((int)t1[0]) };
        hi = (f32x2){ __int_as_float((int)t0[1]), __int_as_float((int)t1[1]) };
        ai = pk_fma(c.psgn[1], hi, lo);
    }
    zr = pk_fma(ar, c.C[1], ai * c.Sn[1]);
    zi = pk_fma(ai, c.C[1], ar * c.S[1]);
    // ---- stage 2: xor8 via DPP row_ror:8; bfly = sgn*mine + partner ----
    pr.x = dpp_mov<0x128>(zr.x); pr.y = dpp_mov<0x128>(zr.y);
    pi.x = dpp_mov<0x128>(zi.x); pi.y = dpp_mov<0x128>(zi.y);
    ar = pk_fma(c.psgn[2], zr, pr);
    ai = pk_fma(c.psgn[2], zi, pi);
    zr = pk_fma(ar, c.C[2], ai * c.Sn[2]);
    zi = pk_fma(ai, c.C[2], ar * c.S[2]);
    // ---- stage 3: xor4 via ds_swizzle ----
    pr.x = swz4(zr.x); pr.y = swz4(zr.y);
    pi.x = swz4(zi.x); pi.y = swz4(zi.y);
    ar = pk_fma(c.psgn[3], zr, pr);
    ai = pk_fma(c.psgn[3], zi, pi);
    zr = pk_fma(ar, c.C[3], ai * c.Sn[3]);
    zi = pk_fma(ai, c.C[3], ar * c.S[3]);
    // ---- stage 4: xor2 via DPP quad_perm [2,3,0,1]; twiddle is 1 or -i ----
    pr.x = dpp_mov<0x4E>(zr.x); pr.y = dpp_mov<0x4E>(zr.y);
    pi.x = dpp_mov<0x4E>(zi.x); pi.y = dpp_mov<0x4E>(zi.y);
    ar = pk_fma(c.psgn[4], zr, pr);
    ai = pk_fma(c.psgn[4], zi, pi);
    zr = c.rot4 ? ai : ar;          // (ar + i*ai) * (-i) = ai - i*ar
    zi = c.rot4 ? -ar : ai;
    // ---- stage 5: xor1 via DPP quad_perm [1,0,3,2]; twiddle == 1 ----
    pr.x = dpp_mov<0xB1>(zr.x); pr.y = dpp_mov<0xB1>(zr.y);
    pi.x = dpp_mov<0xB1>(zi.x); pi.y = dpp_mov<0xB1>(zi.y);
    zr = pk_fma(c.psgn[5], zr, pr);
    zi = pk_fma(c.psgn[5], zi, pi);
}

// packed epilogue for a row pair — cached stores (R10)
template <bool STORE_PAIR>
__device__ __forceinline__ void epilogue_pair(f32x2 zr, f32x2 zi,
                                              float* __restrict__ out,
                                              int r0, const LaneConst& c) {
    f32x2 p0r = { rdlane(zr.x, 52), rdlane(zr.y, 52) };
    f32x2 p0i = { rdlane(zi.x, 52), rdlane(zi.y, 52) };
    f32x2 p1r = { rdlane(zr.x, 38), rdlane(zr.y, 38) };
    f32x2 p1i = { rdlane(zi.x, 38), rdlane(zi.y, 38) };
    f32x2 p2r = { rdlane(zr.x, 57), rdlane(zr.y, 57) };
    f32x2 p2i = { rdlane(zi.x, 57), rdlane(zi.y, 57) };
    f32x2 p3r = { rdlane(zr.x, 43), rdlane(zr.y, 43) };
    f32x2 p3i = { rdlane(zi.x, 43), rdlane(zi.y, 43) };
    f32x2 hr = c.pw0 * p0r;
    hr = pk_fma(c.pw1, p1r, hr);
    hr = pk_fma(c.pw2, p2r, hr);
    hr = pk_fma(c.pw3, p3r, hr);
    f32x2 hi = c.pw0 * p0i;
    hi = pk_fma(c.pw1, p1i, hi);
    hi = pk_fma(c.pw2, p2i, hi);
    hi = pk_fma(c.pw3, p3i, hi);
    f32x2 den = pk_fma(hr, hr, pk_fma(hi, hi, (f32x2){1e-8f, 1e-8f}));
    f32x2 rd;
    rd.x = __builtin_amdgcn_rcpf(den.x);
    rd.y = __builtin_amdgcn_rcpf(den.y);
    f32x2 numr = pk_fma(zr, hr, zi * hi);
    f32x2 numi = pk_fma(zi, hr, zr * (-hi));
    f32x2 eqr = numr * rd;
    f32x2 eqi = numi * rd;
    float* po0 = out + (size_t)r0 * 128;
    po0[c.kk]      = eqr.x;
    po0[64 + c.kk] = eqi.x;
    if (STORE_PAIR) {
        float* po1 = po0 + 128;
        po1[c.kk]      = eqr.y;
        po1[64 + c.kk] = eqi.y;
    }
}

__device__ __forceinline__ void do_rows8(const float* __restrict__ x,
                                         float* __restrict__ out,
                                         int r0, int lane, const LaneConst& c) {
    float xr[8], xi[8];
    #pragma unroll
    for (int j = 0; j < 8; ++j) {
        const float* px = x + (size_t)(r0 + j) * 128;
        xr[j] = __builtin_nontemporal_load(px + lane);       // NT: keep input out of L3
        xi[j] = __builtin_nontemporal_load(px + 64 + lane);
    }
    #pragma unroll
    for (int p = 0; p < 4; ++p) {
        f32x2 zr = { xr[2 * p], xr[2 * p + 1] };
        f32x2 zi = { xi[2 * p], xi[2 * p + 1] };
        fft_pair(zr, zi, c);
        epilogue_pair<true>(zr, zi, out, r0 + 2 * p, c);
    }
}

__global__ __launch_bounds__(256) void ofdm_kernel(const float* __restrict__ x,
                                                   float* __restrict__ out,
                                                   int nrows) {
    const int lane = threadIdx.x & 63;
    const int wid  = threadIdx.x >> 6;
    const int wavesPerBlock = blockDim.x >> 6;
    const int gw = blockIdx.x * wavesPerBlock + wid;
    const int gstride = gridDim.x * wavesPerBlock;

    LaneConst c;
    #pragma unroll
    for (int s = 0; s < 6; ++s) {
        const int half = 32 >> s;
        const bool up = (lane & half) != 0;
        const float sg = up ? -1.0f : 1.0f;
        c.psgn[s] = (f32x2){sg, sg};
        if (s < 4) {
            const int t = (lane & (half - 1)) << s;
            // v_cos_f32 / v_sin_f32 take REVOLUTIONS: t*(pi/32) rad == t/64 rev
            const float fr = (float)t * 0.015625f;
            const float cc = up ? __builtin_amdgcn_cosf(fr) : 1.0f;
            const float ss = up ? -__builtin_amdgcn_sinf(fr) : 0.0f; // W = e^{-i th}
            c.C[s]  = (f32x2){cc, cc};
            c.S[s]  = (f32x2){ss, ss};
            c.Sn[s] = (f32x2){-ss, -ss};
        }
    }
    // stage 4: t = (lane&1)<<4 -> theta in {0, pi/2}; up lanes with t=16: *-i
    c.rot4 = ((lane & 2) != 0) && ((lane & 1) != 0);

    c.kk = (int)(__brev((unsigned)lane) >> 26);
    const int seg = (c.kk <= 25) ? 0 : (c.kk <= 39) ? 1 : 2; // pilots 11,25,39,53
    float a = (float)(c.kk - (11 + seg * 14)) * (1.0f / 14.0f);
    a = fminf(fmaxf(a, 0.0f), 1.0f);
    float w0 = 0, w1 = 0, w2 = 0, w3 = 0;
    const float wa = 1.0f - a, wb = a;
    if (seg == 0) { w0 = wa; w1 = wb; }
    else if (seg == 1) { w1 = wa; w2 = wb; }
    else { w2 = wa; w3 = wb; }
    c.pw0 = (f32x2){w0, w0}; c.pw1 = (f32x2){w1, w1};
    c.pw2 = (f32x2){w2, w2}; c.pw3 = (f32x2){w3, w3};

    const int step = gstride * 8;
    int r = gw * 8;
    for (; r + 8 <= nrows; r += step)
        do_rows8(x, out, r, lane, c);

    // tail (unused for nrows % 8 == 0): strided row pairs, then odd row
    const int tail = nrows & ~7;
    for (int rr = tail + gw * 2; rr + 2 <= nrows; rr += gstride * 2) {
        const float* p0 = x + (size_t)rr * 128;
        f32x2 zr = { __builtin_nontemporal_load(p0 + lane),
                     __builtin_nontemporal_load(p0 + 128 + lane) };
        f32x2 zi = { __builtin_nontemporal_load(p0 + 64 + lane),
                     __builtin_nontemporal_load(p0 + 192 + lane) };
        fft_pair(zr, zi, c);
        epilogue_pair<true>(zr, zi, out, rr, c);
    }
    if ((nrows & 1) && gw == 0) {
        const int rr = nrows - 1;
        const float* p0 = x + (size_t)rr * 128;
        f32x2 zr = { __builtin_nontemporal_load(p0 + lane),
                     __builtin_nontemporal_load(p0 + lane) };
        f32x2 zi = { __builtin_nontemporal_load(p0 + 64 + lane),
                     __builtin_nontemporal_load(p0 + 64 + lane) };
        fft_pair(zr, zi, c);
        epilogue_pair<false>(zr, zi, out, rr, c);
    }
}

extern "C" void kernel_launch(void* const* d_in, const int* in_sizes, int n_in,
                              void* d_out, int out_size, void* d_ws, size_t ws_size,
                              hipStream_t stream) {
    const float* x = (const float*)d_in[0];
    float* out = (float*)d_out;
    const int nrows = in_sizes[0] / 128;   // 262144
    const int block = 256;                 // 4 waves/block
    const int grid = 2048;                 // 8192 waves, 4 iters x 8 rows
    hipLaunchKernelGGL(ofdm_kernel, dim3(grid), dim3(block), 0, stream,
                       x, out, nrows);
}

// Round 13
// 45.773 us; speedup vs baseline: 1.0706x; 1.0706x over previous
//
#include <hip/hip_runtime.h>
#include <math.h>

// OFDM: per-row 64-pt complex FFT (radix-2 DIF, lane-per-bin), fully
// row-PAIR packed (v_pk_fma_f32 via compiler; no inline asm).
// Cross-lane per 32-bit reg: xor32 -> permlane32_swap, xor16 ->
// permlane16_swap, xor8 -> DPP row_ror:8, xor4 -> ds_swizzle,
// xor2/xor1 -> DPP quad_perm. Stage-4 twiddle = +/-i -> selects.
// R12: bit-reversed scatter-stores (4B/lane, address-divergent) replaced by
// wave-private LDS staging: scatter into LDS (2-way bank alias = free),
// ds_read_b128 linear, ONE global_store_dwordx4 per lane per row pair
// (16B/lane fully coalesced). Same-wave DS ops are in-order -> no barrier.
// Loads stay cached dwords (65MB of 134MB served by L3 - R11 showed NT
// loads forfeit those hits).

typedef float f32x2 __attribute__((ext_vector_type(2)));
typedef float f32x4 __attribute__((ext_vector_type(4)));
typedef unsigned int uint2v __attribute__((ext_vector_type(2)));

struct LaneConst {
    f32x2 psgn[6];            // stages 0..5 butterfly sign (broadcast pair)
    f32x2 C[4], S[4], Sn[4];  // stages 0..3 twiddle (S = -sin; stage4 = +/-i, stage5 = 1)
    bool  rot4;               // stage-4: this lane multiplies by -i
    f32x2 pw0, pw1, pw2, pw3; // pilot interp weights (broadcast pair)
    int   kk;                 // natural bin index = brev6(lane)
};

__device__ __forceinline__ f32x2 pk_fma(f32x2 a, f32x2 b, f32x2 cc) {
#if __has_builtin(__builtin_elementwise_fma)
    return __builtin_elementwise_fma(a, b, cc);
#else
    return a * b + cc;
#endif
}

template <int CTRL>
__device__ __forceinline__ float dpp_mov(float x) {
    return __int_as_float(__builtin_amdgcn_update_dpp(
        0, __float_as_int(x), CTRL, 0xF, 0xF, true));
}
__device__ __forceinline__ float swz4(float x) {
    return __int_as_float(__builtin_amdgcn_ds_swizzle(__float_as_int(x), 0x101F));
}
__device__ __forceinline__ float rdlane(float x, int l) {
    return __int_as_float(__builtin_amdgcn_readlane(__float_as_int(x), l));
}

// full packed FFT for a row pair (rows r0, r0+1 in .x/.y of zr, zi)
__device__ __forceinline__ void fft_pair(f32x2& zr, f32x2& zi, const LaneConst& c) {
    f32x2 lo, hi, ar, ai, pr, pi;
    // ---- stage 0: xor32 via permlane32_swap; bfly = sgn*hi + lo ----
    {
        uint2v t0 = __builtin_amdgcn_permlane32_swap(
            (unsigned)__float_as_int(zr.x), (unsigned)__float_as_int(zr.x), false, false);
        uint2v t1 = __builtin_amdgcn_permlane32_swap(
            (unsigned)__float_as_int(zr.y), (unsigned)__float_as_int(zr.y), false, false);
        lo = (f32x2){ __int_as_float((int)t0[0]), __int_as_float((int)t1[0]) };
        hi = (f32x2){ __int_as_float((int)t0[1]), __int_as_float((int)t1[1]) };
        ar = pk_fma(c.psgn[0], hi, lo);
        t0 = __builtin_amdgcn_permlane32_swap(
            (unsigned)__float_as_int(zi.x), (unsigned)__float_as_int(zi.x), false, false);
        t1 = __builtin_amdgcn_permlane32_swap(
            (unsigned)__float_as_int(zi.y), (unsigned)__float_as_int(zi.y), false, false);
        lo = (f32x2){ __int_as_float((int)t0[0]), __int_as_float((int)t1[0]) };
        hi = (f32x2){ __int_as_float((int)t0[1]), __int_as_float((int)t1[1]) };
        ai = pk_fma(c.psgn[0], hi, lo);
    }
    zr = pk_fma(ar, c.C[0], ai * c.Sn[0]);
    zi = pk_fma(ai, c.C[0], ar * c.S[0]);
    // ---- stage 1: xor16 via permlane16_swap ----
    {
        uint2v t0 = __builtin_amdgcn_permlane16_swap(
            (unsigned)__float_as_int(zr.x), (unsigned)__float_as_int(zr.x), false, false);
        uint2v t1 = __builtin_amdgcn_permlane16_swap(
            (unsigned)__float_as_int(zr.y), (unsigned)__float_as_int(zr.y), false, false);
        lo = (f32x2){ __int_as_float((int)t0[0]), __int_as_float((int)t1[0]) };
        hi = (f32x2){ __int_as_float((int)t0[1]), __int_as_float((int)t1[1]) };
        ar = pk_fma(c.psgn[1], hi, lo);
        t0 = __builtin_amdgcn_permlane16_swap(
            (unsigned)__float_as_int(zi.x), (unsigned)__float_as_int(zi.x), false, false);
        t1 = __builtin_amdgcn_permlane16_swap(
            (unsigned)__float_as_int(zi.y), (unsigned)__float_as_int(zi.y), false, false);
        lo = (f32x2){ __int_as_float((int)t0[0]), __int_as_float((int)t1[0]) };
        hi = (f32x2){ __int_as_float((int)t0[1]), __int_as_float((int)t1[1]) };
        ai = pk_fma(c.psgn[1], hi, lo);
    }
    zr = pk_fma(ar, c.C[1], ai * c.Sn[1]);
    zi = pk_fma(ai, c.C[1], ar * c.S[1]);
    // ---- stage 2: xor8 via DPP row_ror:8; bfly = sgn*mine + partner ----
    pr.x = dpp_mov<0x128>(zr.x); pr.y = dpp_mov<0x128>(zr.y);
    pi.x = dpp_mov<0x128>(zi.x); pi.y = dpp_mov<0x128>(zi.y);
    ar = pk_fma(c.psgn[2], zr, pr);
    ai = pk_fma(c.psgn[2], zi, pi);
    zr = pk_fma(ar, c.C[2], ai * c.Sn[2]);
    zi = pk_fma(ai, c.C[2], ar * c.S[2]);
    // ---- stage 3: xor4 via ds_swizzle ----
    pr.x = swz4(zr.x); pr.y = swz4(zr.y);
    pi.x = swz4(zi.x); pi.y = swz4(zi.y);
    ar = pk_fma(c.psgn[3], zr, pr);
    ai = pk_fma(c.psgn[3], zi, pi);
    zr = pk_fma(ar, c.C[3], ai * c.Sn[3]);
    zi = pk_fma(ai, c.C[3], ar * c.S[3]);
    // ---- stage 4: xor2 via DPP quad_perm [2,3,0,1]; twiddle is 1 or -i ----
    pr.x = dpp_mov<0x4E>(zr.x); pr.y = dpp_mov<0x4E>(zr.y);
    pi.x = dpp_mov<0x4E>(zi.x); pi.y = dpp_mov<0x4E>(zi.y);
    ar = pk_fma(c.psgn[4], zr, pr);
    ai = pk_fma(c.psgn[4], zi, pi);
    zr = c.rot4 ? ai : ar;          // (ar + i*ai) * (-i) = ai - i*ar
    zi = c.rot4 ? -ar : ai;
    // ---- stage 5: xor1 via DPP quad_perm [1,0,3,2]; twiddle == 1 ----
    pr.x = dpp_mov<0xB1>(zr.x); pr.y = dpp_mov<0xB1>(zr.y);
    pi.x = dpp_mov<0xB1>(zi.x); pi.y = dpp_mov<0xB1>(zi.y);
    zr = pk_fma(c.psgn[5], zr, pr);
    zi = pk_fma(c.psgn[5], zi, pi);
}

// packed epilogue math only (no stores): returns eqr/eqi for the pair
__device__ __forceinline__ void eq_pair(f32x2 zr, f32x2 zi,
                                        f32x2& eqr, f32x2& eqi,
                                        const LaneConst& c) {
    f32x2 p0r = { rdlane(zr.x, 52), rdlane(zr.y, 52) };
    f32x2 p0i = { rdlane(zi.x, 52), rdlane(zi.y, 52) };
    f32x2 p1r = { rdlane(zr.x, 38), rdlane(zr.y, 38) };
    f32x2 p1i = { rdlane(zi.x, 38), rdlane(zi.y, 38) };
    f32x2 p2r = { rdlane(zr.x, 57), rdlane(zr.y, 57) };
    f32x2 p2i = { rdlane(zi.x, 57), rdlane(zi.y, 57) };
    f32x2 p3r = { rdlane(zr.x, 43), rdlane(zr.y, 43) };
    f32x2 p3i = { rdlane(zi.x, 43), rdlane(zi.y, 43) };
    f32x2 hr = c.pw0 * p0r;
    hr = pk_fma(c.pw1, p1r, hr);
    hr = pk_fma(c.pw2, p2r, hr);
    hr = pk_fma(c.pw3, p3r, hr);
    f32x2 hi = c.pw0 * p0i;
    hi = pk_fma(c.pw1, p1i, hi);
    hi = pk_fma(c.pw2, p2i, hi);
    hi = pk_fma(c.pw3, p3i, hi);
    f32x2 den = pk_fma(hr, hr, pk_fma(hi, hi, (f32x2){1e-8f, 1e-8f}));
    f32x2 rd;
    rd.x = __builtin_amdgcn_rcpf(den.x);
    rd.y = __builtin_amdgcn_rcpf(den.y);
    eqr = pk_fma(zr, hr, zi * hi) * rd;
    eqi = pk_fma(zi, hr, zr * (-hi)) * rd;
}

// LDS-staged coalesced store of one row pair (1KB contiguous, 16B/lane).
// L = per-wave 256-float scratch. Same-wave DS ops are in-order; the
// compiler orders them via aliasing on the same __shared__ array.
__device__ __forceinline__ void store_pair_coalesced(f32x2 eqr, f32x2 eqi,
                                                     float* __restrict__ L,
                                                     float* __restrict__ out,
                                                     int r0, int lane,
                                                     const LaneConst& c) {
    L[c.kk]       = eqr.x;   // row0 eq_r[kk]
    L[64 + c.kk]  = eqi.x;   // row0 eq_i[kk]
    L[128 + c.kk] = eqr.y;   // row1 eq_r[kk]
    L[192 + c.kk] = eqi.y;   // row1 eq_i[kk]
    const f32x4 v = *(const f32x4*)(L + 4 * lane);       // ds_read_b128, linear
    *(f32x4*)(out + (size_t)r0 * 128 + 4 * lane) = v;    // global_store_dwordx4
}

__device__ __forceinline__ void do_rows8(const float* __restrict__ x,
                                         float* __restrict__ out,
                                         float* __restrict__ L,
                                         int r0, int lane, const LaneConst& c) {
    float xr[8], xi[8];
    #pragma unroll
    for (int j = 0; j < 8; ++j) {
        const float* px = x + (size_t)(r0 + j) * 128;
        xr[j] = px[lane];
        xi[j] = px[64 + lane];
    }
    #pragma unroll
    for (int p = 0; p < 4; ++p) {
        f32x2 zr = { xr[2 * p], xr[2 * p + 1] };
        f32x2 zi = { xi[2 * p], xi[2 * p + 1] };
        fft_pair(zr, zi, c);
        f32x2 eqr, eqi;
        eq_pair(zr, zi, eqr, eqi, c);
        store_pair_coalesced(eqr, eqi, L, out, r0 + 2 * p, lane, c);
    }
}

__global__ __launch_bounds__(256) void ofdm_kernel(const float* __restrict__ x,
                                                   float* __restrict__ out,
                                                   int nrows) {
    __shared__ float lds[4][256];   // 1KB per wave
    const int lane = threadIdx.x & 63;
    const int wid  = threadIdx.x >> 6;
    const int wavesPerBlock = blockDim.x >> 6;
    const int gw = blockIdx.x * wavesPerBlock + wid;
    const int gstride = gridDim.x * wavesPerBlock;
    float* L = &lds[wid][0];

    LaneConst c;
    #pragma unroll
    for (int s = 0; s < 6; ++s) {
        const int half = 32 >> s;
        const bool up = (lane & half) != 0;
        const float sg = up ? -1.0f : 1.0f;
        c.psgn[s] = (f32x2){sg, sg};
        if (s < 4) {
            const int t = (lane & (half - 1)) << s;
            // v_cos_f32 / v_sin_f32 take REVOLUTIONS: t*(pi/32) rad == t/64 rev
            const float fr = (float)t * 0.015625f;
            const float cc = up ? __builtin_amdgcn_cosf(fr) : 1.0f;
            const float ss = up ? -__builtin_amdgcn_sinf(fr) : 0.0f; // W = e^{-i th}
            c.C[s]  = (f32x2){cc, cc};
            c.S[s]  = (f32x2){ss, ss};
            c.Sn[s] = (f32x2){-ss, -ss};
        }
    }
    // stage 4: t = (lane&1)<<4 -> theta in {0, pi/2}; up lanes with t=16: *-i
    c.rot4 = ((lane & 2) != 0) && ((lane & 1) != 0);

    c.kk = (int)(__brev((unsigned)lane) >> 26);
    const int seg = (c.kk <= 25) ? 0 : (c.kk <= 39) ? 1 : 2; // pilots 11,25,39,53
    float a = (float)(c.kk - (11 + seg * 14)) * (1.0f / 14.0f);
    a = fminf(fmaxf(a, 0.0f), 1.0f);
    float w0 = 0, w1 = 0, w2 = 0, w3 = 0;
    const float wa = 1.0f - a, wb = a;
    if (seg == 0) { w0 = wa; w1 = wb; }
    else if (seg == 1) { w1 = wa; w2 = wb; }
    else { w2 = wa; w3 = wb; }
    c.pw0 = (f32x2){w0, w0}; c.pw1 = (f32x2){w1, w1};
    c.pw2 = (f32x2){w2, w2}; c.pw3 = (f32x2){w3, w3};

    const int step = gstride * 8;
    int r = gw * 8;
    for (; r + 8 <= nrows; r += step)
        do_rows8(x, out, L, r, lane, c);

    // tail (unused for nrows % 8 == 0): strided row pairs, then odd row
    const int tail = nrows & ~7;
    for (int rr = tail + gw * 2; rr + 2 <= nrows; rr += gstride * 2) {
        const float* p0 = x + (size_t)rr * 128;
        f32x2 zr = { p0[lane],      p0[128 + lane] };
        f32x2 zi = { p0[64 + lane], p0[192 + lane] };
        fft_pair(zr, zi, c);
        f32x2 eqr, eqi;
        eq_pair(zr, zi, eqr, eqi, c);
        store_pair_coalesced(eqr, eqi, L, out, rr, lane, c);
    }
    if ((nrows & 1) && gw == 0) {
        const int rr = nrows - 1;
        const float* p0 = x + (size_t)rr * 128;
        f32x2 zr = { p0[lane], p0[lane] };
        f32x2 zi = { p0[64 + lane], p0[64 + lane] };
        fft_pair(zr, zi, c);
        f32x2 eqr, eqi;
        eq_pair(zr, zi, eqr, eqi, c);
        float* po = out + (size_t)rr * 128;
        po[c.kk]      = eqr.x;    // scalar stores for the lone odd row
        po[64 + c.kk] = eqi.x;
    }
}

extern "C" void kernel_launch(void* const* d_in, const int* in_sizes, int n_in,
                              void* d_out, int out_size, void* d_ws, size_t ws_size,
                              hipStream_t stream) {
    const float* x = (const float*)d_in[0];
    float* out = (float*)d_out;
    const int nrows = in_sizes[0] / 128;   // 262144
    const int block = 256;                 // 4 waves/block
    const int grid = 2048;                 // 8192 waves, 4 iters x 8 rows
    hipLaunchKernelGGL(ofdm_kernel, dim3(grid), dim3(block), 0, stream,
                       x, out, nrows);
}